// Round 1
// baseline (726.488 us; speedup 1.0000x reference)
//
#include <hip/hip_runtime.h>

#define B_    16
#define T_    4096
#define D_    1024
#define CD_   8
#define CS_   1024
#define NROWS 65536
#define EPSF  1e-12f

// ---- d_out float offsets (outputs concatenated flat in return order) ----
#define OUT_OFF    0           // [16,4096,1024] = 67108864
#define COMMIT_OFF 67108864    // [16]
#define CBLOSS_OFF 67108880    // [16]
#define IDX_OFF    67108896    // [16,4096] as float
#define ZE_OFF     67174432    // [16,4096,8]

// ---- ws float offsets ----
#define WS_INWT 0        // in_wT  [8][1024]  (c-major)
#define WS_CBNT 8192     // cbnT   [8][1024]  (c-major, normalized codebook)
#define WS_OUTW 16384    // out_w  [8][1024]  (c-major, == out_v layout)
#define WS_CN2  24576    // ||cbn_j||^2 [1024]
#define WS_IDX  25600    // indices as int [65536]

// ---------------------------------------------------------------------------
// Prep: weight-norm both matrices, normalize codebook (transposed), zero losses
// ---------------------------------------------------------------------------
__global__ __launch_bounds__(1024)
void vq_prep(const float* __restrict__ in_v, const float* __restrict__ in_g,
             const float* __restrict__ out_v, const float* __restrict__ out_g,
             const float* __restrict__ cb, float* __restrict__ ws,
             float* __restrict__ dout) {
    int t = threadIdx.x;
    int lane = t & 63;
    int wid = t >> 6;
    __shared__ float normIn[CD_];

    // column norms of in_v (sum over d per c): wave w handles column w
    if (wid < CD_) {
        float s = 0.f;
        #pragma unroll
        for (int i = 0; i < D_ / 64; ++i) {
            float v = in_v[(size_t)(lane + 64 * i) * CD_ + wid];
            s = fmaf(v, v, s);
        }
        #pragma unroll
        for (int m = 1; m <= 32; m <<= 1) s += __shfl_xor(s, m, 64);
        if (lane == 0) normIn[wid] = sqrtf(s);
    }
    __syncthreads();

    // in_wT[c][d] = in_g[c] * in_v[d][c] / max(eps, norm_c)
    #pragma unroll
    for (int rep = 0; rep < (CD_ * D_) / 1024; ++rep) {
        int idx = rep * 1024 + t;
        int c = idx >> 10, d = idx & (D_ - 1);
        ws[WS_INWT + idx] = in_g[c] * in_v[(size_t)d * CD_ + c] / fmaxf(EPSF, normIn[c]);
    }

    // out_w[c][d] = out_g[d] * out_v[c][d] / max(eps, norm_d)   (norm over c)
    {
        int d = t;  // blockDim == 1024 == D_
        float v[CD_]; float s = 0.f;
        #pragma unroll
        for (int c = 0; c < CD_; ++c) { v[c] = out_v[c * D_ + d]; s = fmaf(v[c], v[c], s); }
        float n = fmaxf(EPSF, sqrtf(s));
        float g = out_g[d];
        #pragma unroll
        for (int c = 0; c < CD_; ++c) ws[WS_OUTW + c * D_ + d] = g * v[c] / n;
    }

    // cbnT[c][j] = cb[j][c] / max(eps, ||cb_j||);  cn2[j] = sum_c cbnT^2
    {
        int j = t;  // blockDim == 1024 == CS_
        float v[CD_]; float s = 0.f;
        #pragma unroll
        for (int c = 0; c < CD_; ++c) { v[c] = cb[j * CD_ + c]; s = fmaf(v[c], v[c], s); }
        float n = fmaxf(EPSF, sqrtf(s));
        float n2 = 0.f;
        #pragma unroll
        for (int c = 0; c < CD_; ++c) {
            float q = v[c] / n;
            ws[WS_CBNT + c * CS_ + j] = q;
            n2 = fmaf(q, q, n2);
        }
        ws[WS_CN2 + j] = n2;
    }

    // zero the 32 loss accumulators (poisoned + atomically accumulated)
    if (t < 32) dout[COMMIT_OFF + t] = 0.f;
}

// ---------------------------------------------------------------------------
// Main VQ: z_e = z @ in_wT + in_b ; nearest code (cosine) ; losses ; z_e, idx
// One wave processes 4 consecutive rows per pass (amortizes LDS sweeps 4x).
// ---------------------------------------------------------------------------
__global__ __launch_bounds__(512)
void vq_main(const float* __restrict__ z, const float* __restrict__ in_b,
             const float* __restrict__ cb, const float* __restrict__ ws,
             float* __restrict__ dout, int* __restrict__ idx_out) {
    __shared__ float lds[16384];  // [0,8192)=in_wT  [8192,16384)=cbnT  (64 KB)
    int t = threadIdx.x;

    #pragma unroll
    for (int i = 0; i < 8; ++i) {
        int idx = i * 512 + t;
        ((float4*)lds)[idx] = ((const float4*)ws)[idx];
    }
    __syncthreads();

    int lane = t & 63;
    int wv = (blockIdx.x << 3) + (t >> 6);  // 0..4095

    float bia[CD_];
    #pragma unroll
    for (int c = 0; c < CD_; ++c) bia[c] = in_b[c];
    float4 cn2[4];
    #pragma unroll
    for (int m = 0; m < 4; ++m)
        cn2[m] = *(const float4*)(ws + WS_CN2 + (m << 8) + (lane << 2));

    for (int it = 0; it < 4; ++it) {
        int bi = wv + (it << 12);   // 0..16383
        int row0 = bi << 2;         // 4 consecutive rows, same batch b

        // ---- z_e partial dot over this lane's d-slices ----
        float ze[4][CD_];
        #pragma unroll
        for (int r = 0; r < 4; ++r)
            #pragma unroll
            for (int c = 0; c < CD_; ++c) ze[r][c] = 0.f;

        #pragma unroll
        for (int k = 0; k < 4; ++k) {
            float4 zv[4];
            #pragma unroll
            for (int r = 0; r < 4; ++r)
                zv[r] = *(const float4*)(z + (size_t)(row0 + r) * D_ + (k << 8) + (lane << 2));
            #pragma unroll
            for (int c = 0; c < CD_; ++c) {
                float4 w4 = *(const float4*)(lds + c * D_ + (k << 8) + (lane << 2));
                #pragma unroll
                for (int r = 0; r < 4; ++r) {
                    ze[r][c] = fmaf(zv[r].x, w4.x, ze[r][c]);
                    ze[r][c] = fmaf(zv[r].y, w4.y, ze[r][c]);
                    ze[r][c] = fmaf(zv[r].z, w4.z, ze[r][c]);
                    ze[r][c] = fmaf(zv[r].w, w4.w, ze[r][c]);
                }
            }
        }

        // ---- wave-sum each of the 32 partials (replicates z_e on all lanes) ----
        #pragma unroll
        for (int r = 0; r < 4; ++r) {
            #pragma unroll
            for (int c = 0; c < CD_; ++c) {
                float v = ze[r][c];
                v += __shfl_xor(v, 1, 64);
                v += __shfl_xor(v, 2, 64);
                v += __shfl_xor(v, 4, 64);
                v += __shfl_xor(v, 8, 64);
                v += __shfl_xor(v, 16, 64);
                v += __shfl_xor(v, 32, 64);
                ze[r][c] = v + bia[c];
            }
        }

        // ---- row norms; fold 1/||ze|| into the score instead of materializing enc ----
        float tw[4];
        #pragma unroll
        for (int r = 0; r < 4; ++r) {
            float s = 0.f;
            #pragma unroll
            for (int c = 0; c < CD_; ++c) s = fmaf(ze[r][c], ze[r][c], s);
            tw[r] = 2.f / fmaxf(EPSF, sqrtf(s));
        }

        // ---- scan 1024 codes: lane handles j = 4*lane + 256*m (+e) ----
        float bs[4] = {-1e38f, -1e38f, -1e38f, -1e38f};
        int   bj[4] = {0, 0, 0, 0};
        #pragma unroll
        for (int m = 0; m < 4; ++m) {
            float dt0[4], dt1[4], dt2[4], dt3[4];
            #pragma unroll
            for (int r = 0; r < 4; ++r) { dt0[r] = dt1[r] = dt2[r] = dt3[r] = 0.f; }
            #pragma unroll
            for (int c = 0; c < CD_; ++c) {
                float4 v4 = *(const float4*)(lds + CD_ * D_ + c * CS_ + (m << 8) + (lane << 2));
                #pragma unroll
                for (int r = 0; r < 4; ++r) {
                    dt0[r] = fmaf(v4.x, ze[r][c], dt0[r]);
                    dt1[r] = fmaf(v4.y, ze[r][c], dt1[r]);
                    dt2[r] = fmaf(v4.z, ze[r][c], dt2[r]);
                    dt3[r] = fmaf(v4.w, ze[r][c], dt3[r]);
                }
            }
            int j0 = (m << 8) + (lane << 2);
            #pragma unroll
            for (int r = 0; r < 4; ++r) {
                float s0 = fmaf(dt0[r], tw[r], -cn2[m].x);
                if (s0 > bs[r]) { bs[r] = s0; bj[r] = j0; }
                float s1 = fmaf(dt1[r], tw[r], -cn2[m].y);
                if (s1 > bs[r]) { bs[r] = s1; bj[r] = j0 + 1; }
                float s2 = fmaf(dt2[r], tw[r], -cn2[m].z);
                if (s2 > bs[r]) { bs[r] = s2; bj[r] = j0 + 2; }
                float s3 = fmaf(dt3[r], tw[r], -cn2[m].w);
                if (s3 > bs[r]) { bs[r] = s3; bj[r] = j0 + 3; }
            }
        }

        // ---- cross-lane argmax (tie -> smaller j, matches np.argmax first-max) ----
        #pragma unroll
        for (int r = 0; r < 4; ++r) {
            #pragma unroll
            for (int mlog = 0; mlog < 6; ++mlog) {
                int mk = 1 << mlog;
                float os = __shfl_xor(bs[r], mk, 64);
                int   oj = __shfl_xor(bj[r], mk, 64);
                bool take = (os > bs[r]) || (os == bs[r] && oj < bj[r]);
                bs[r] = take ? os : bs[r];
                bj[r] = take ? oj : bj[r];
            }
        }

        // ---- losses: sum (z_e - z_q)^2 over 4 rows x 8 dims ----
        float lsum = 0.f;
        #pragma unroll
        for (int r = 0; r < 4; ++r) {
            #pragma unroll
            for (int c = 0; c < CD_; ++c) {
                float q = cb[bj[r] * CD_ + c];   // raw codebook (broadcast load)
                float d = ze[r][c] - q;
                lsum = fmaf(d, d, lsum);
            }
        }
        if (lane == 0) {
            float v = lsum * (1.f / 32768.f);   // mean over T*CD per batch b
            int b = row0 >> 12;
            atomicAdd(dout + COMMIT_OFF + b, v);
            atomicAdd(dout + CBLOSS_OFF + b, v);
        }

        // ---- write z_e + indices (static register indices: one lane per row) ----
        #pragma unroll
        for (int r = 0; r < 4; ++r) {
            if (lane == r) {
                float4 a = make_float4(ze[r][0], ze[r][1], ze[r][2], ze[r][3]);
                float4 b4 = make_float4(ze[r][4], ze[r][5], ze[r][6], ze[r][7]);
                *(float4*)(dout + ZE_OFF + (size_t)(row0 + r) * CD_) = a;
                *(float4*)(dout + ZE_OFF + (size_t)(row0 + r) * CD_ + 4) = b4;
                dout[IDX_OFF + row0 + r] = (float)bj[r];
                idx_out[row0 + r] = bj[r];
            }
        }
    }
}

// ---------------------------------------------------------------------------
// Out projection: out = codebook[idx] @ out_w + out_b   (write-bound)
// ---------------------------------------------------------------------------
__global__ __launch_bounds__(256)
void vq_out(const float* __restrict__ cb, const float* __restrict__ ws,
            const float* __restrict__ out_b, const int* __restrict__ idx,
            float* __restrict__ out) {
    int t = threadIdx.x;
    int lane = t & 63;
    int wv = (blockIdx.x << 2) + (t >> 6);  // 0..4095
    const float* ow = ws + WS_OUTW;

    float4 ob[4];
    #pragma unroll
    for (int k = 0; k < 4; ++k)
        ob[k] = *(const float4*)(out_b + (k << 8) + (lane << 2));

    for (int it = 0; it < 4; ++it) {
        int bi = wv + (it << 12);
        int row0 = bi << 2;

        float zq[4][CD_];
        #pragma unroll
        for (int r = 0; r < 4; ++r) {
            int j = idx[row0 + r];
            #pragma unroll
            for (int c = 0; c < CD_; ++c) zq[r][c] = cb[j * CD_ + c];
        }

        #pragma unroll
        for (int k = 0; k < 4; ++k) {
            float4 a0 = ob[k], a1 = ob[k], a2 = ob[k], a3 = ob[k];
            #pragma unroll
            for (int c = 0; c < CD_; ++c) {
                float4 w4 = *(const float4*)(ow + c * D_ + (k << 8) + (lane << 2));
                a0.x = fmaf(zq[0][c], w4.x, a0.x); a0.y = fmaf(zq[0][c], w4.y, a0.y);
                a0.z = fmaf(zq[0][c], w4.z, a0.z); a0.w = fmaf(zq[0][c], w4.w, a0.w);
                a1.x = fmaf(zq[1][c], w4.x, a1.x); a1.y = fmaf(zq[1][c], w4.y, a1.y);
                a1.z = fmaf(zq[1][c], w4.z, a1.z); a1.w = fmaf(zq[1][c], w4.w, a1.w);
                a2.x = fmaf(zq[2][c], w4.x, a2.x); a2.y = fmaf(zq[2][c], w4.y, a2.y);
                a2.z = fmaf(zq[2][c], w4.z, a2.z); a2.w = fmaf(zq[2][c], w4.w, a2.w);
                a3.x = fmaf(zq[3][c], w4.x, a3.x); a3.y = fmaf(zq[3][c], w4.y, a3.y);
                a3.z = fmaf(zq[3][c], w4.z, a3.z); a3.w = fmaf(zq[3][c], w4.w, a3.w);
            }
            size_t base = (size_t)row0 * D_ + (k << 8) + (lane << 2);
            *(float4*)(out + base)            = a0;
            *(float4*)(out + base + D_)       = a1;
            *(float4*)(out + base + 2 * D_)   = a2;
            *(float4*)(out + base + 3 * D_)   = a3;
        }
    }
}

extern "C" void kernel_launch(void* const* d_in, const int* in_sizes, int n_in,
                              void* d_out, int out_size, void* d_ws, size_t ws_size,
                              hipStream_t stream) {
    const float* z     = (const float*)d_in[0];
    const float* in_v  = (const float*)d_in[1];
    const float* in_g  = (const float*)d_in[2];
    const float* in_b  = (const float*)d_in[3];
    const float* out_v = (const float*)d_in[4];
    const float* out_g = (const float*)d_in[5];
    const float* out_b = (const float*)d_in[6];
    const float* cb    = (const float*)d_in[7];
    float* dout = (float*)d_out;
    float* ws   = (float*)d_ws;
    int* idxp   = (int*)(ws + WS_IDX);

    vq_prep<<<1, 1024, 0, stream>>>(in_v, in_g, out_v, out_g, cb, ws, dout);
    vq_main<<<512, 512, 0, stream>>>(z, in_b, cb, ws, dout, idxp);
    vq_out<<<1024, 256, 0, stream>>>(cb, ws, out_b, idxp, dout + OUT_OFF);
}

// Round 2
// 671.691 us; speedup vs baseline: 1.0816x; 1.0816x over previous
//
#include <hip/hip_runtime.h>

#define B_    16
#define T_    4096
#define D_    1024
#define CD_   8
#define CS_   1024
#define NROWS 65536
#define EPSF  1e-12f

// ---- d_out float offsets (outputs concatenated flat in return order) ----
#define OUT_OFF    0           // [16,4096,1024] = 67108864
#define COMMIT_OFF 67108864    // [16]
#define CBLOSS_OFF 67108880    // [16]
#define IDX_OFF    67108896    // [16,4096] as float
#define ZE_OFF     67174432    // [16,4096,8]

// ---- ws float offsets ----
#define WS_INWT 0        // in_wT  [8][1024]  (c-major)
#define WS_CBNT 8192     // cbnT   [8][1024]  (c-major, normalized codebook)
#define WS_OUTW 16384    // out_w  [8][1024]  (c-major, == out_v layout)
#define WS_CN2  24576    // ||cbn_j||^2 [1024]
#define WS_IDX  25600    // indices as int [65536]

// ---------------------------------------------------------------------------
// Prep: weight-norm both matrices, normalize codebook (transposed), zero losses
// ---------------------------------------------------------------------------
__global__ __launch_bounds__(1024)
void vq_prep(const float* __restrict__ in_v, const float* __restrict__ in_g,
             const float* __restrict__ out_v, const float* __restrict__ out_g,
             const float* __restrict__ cb, float* __restrict__ ws,
             float* __restrict__ dout) {
    int t = threadIdx.x;
    int lane = t & 63;
    int wid = t >> 6;
    __shared__ float normIn[CD_];

    // column norms of in_v (sum over d per c): wave w handles column w
    if (wid < CD_) {
        float s = 0.f;
        #pragma unroll
        for (int i = 0; i < D_ / 64; ++i) {
            float v = in_v[(size_t)(lane + 64 * i) * CD_ + wid];
            s = fmaf(v, v, s);
        }
        #pragma unroll
        for (int m = 1; m <= 32; m <<= 1) s += __shfl_xor(s, m, 64);
        if (lane == 0) normIn[wid] = sqrtf(s);
    }
    __syncthreads();

    // in_wT[c][d] = in_g[c] * in_v[d][c] / max(eps, norm_c)
    #pragma unroll
    for (int rep = 0; rep < (CD_ * D_) / 1024; ++rep) {
        int idx = rep * 1024 + t;
        int c = idx >> 10, d = idx & (D_ - 1);
        ws[WS_INWT + idx] = in_g[c] * in_v[(size_t)d * CD_ + c] / fmaxf(EPSF, normIn[c]);
    }

    // out_w[c][d] = out_g[d] * out_v[c][d] / max(eps, norm_d)   (norm over c)
    {
        int d = t;  // blockDim == 1024 == D_
        float v[CD_]; float s = 0.f;
        #pragma unroll
        for (int c = 0; c < CD_; ++c) { v[c] = out_v[c * D_ + d]; s = fmaf(v[c], v[c], s); }
        float n = fmaxf(EPSF, sqrtf(s));
        float g = out_g[d];
        #pragma unroll
        for (int c = 0; c < CD_; ++c) ws[WS_OUTW + c * D_ + d] = g * v[c] / n;
    }

    // cbnT[c][j] = cb[j][c] / max(eps, ||cb_j||);  cn2[j] = sum_c cbnT^2
    {
        int j = t;  // blockDim == 1024 == CS_
        float v[CD_]; float s = 0.f;
        #pragma unroll
        for (int c = 0; c < CD_; ++c) { v[c] = cb[j * CD_ + c]; s = fmaf(v[c], v[c], s); }
        float n = fmaxf(EPSF, sqrtf(s));
        float n2 = 0.f;
        #pragma unroll
        for (int c = 0; c < CD_; ++c) {
            float q = v[c] / n;
            ws[WS_CBNT + c * CS_ + j] = q;
            n2 = fmaf(q, q, n2);
        }
        ws[WS_CN2 + j] = n2;
    }

    // zero the 32 loss accumulators (poisoned + atomically accumulated)
    if (t < 32) dout[COMMIT_OFF + t] = 0.f;
}

// ---------------------------------------------------------------------------
// Main VQ: z_e = z @ in_wT + in_b ; nearest code (cosine) ; losses ; z_e, idx
// 2 rows per wave per iteration: low register pressure (no scratch), all
// array indices statically unrolled. Math sequence identical to the passing
// round (bit-identical indices).
// ---------------------------------------------------------------------------
__global__ __launch_bounds__(512)
void vq_main(const float* __restrict__ z, const float* __restrict__ in_b,
             const float* __restrict__ cb, const float* __restrict__ ws,
             float* __restrict__ dout, int* __restrict__ idx_out) {
    __shared__ float lds[16384];  // [0,8192)=in_wT  [8192,16384)=cbnT  (64 KB)
    int t = threadIdx.x;

    #pragma unroll
    for (int i = 0; i < 8; ++i) {
        int idx = i * 512 + t;
        ((float4*)lds)[idx] = ((const float4*)ws)[idx];
    }
    __syncthreads();

    int lane = t & 63;
    int wv = (blockIdx.x << 3) + (t >> 6);  // 0..8191

    float bia[CD_];
    #pragma unroll
    for (int c = 0; c < CD_; ++c) bia[c] = in_b[c];
    float4 cn2[4];
    #pragma unroll
    for (int m = 0; m < 4; ++m)
        cn2[m] = *(const float4*)(ws + WS_CN2 + (m << 8) + (lane << 2));

    for (int it = 0; it < 4; ++it) {
        int bi = wv + (it << 13);   // 0..32767
        int row0 = bi << 1;         // 2 consecutive rows, same batch b

        // ---- z_e partial dot over this lane's d-slices ----
        float ze[2][CD_];
        #pragma unroll
        for (int r = 0; r < 2; ++r)
            #pragma unroll
            for (int c = 0; c < CD_; ++c) ze[r][c] = 0.f;

        #pragma unroll
        for (int k = 0; k < 4; ++k) {
            float4 zv0 = *(const float4*)(z + (size_t)(row0)     * D_ + (k << 8) + (lane << 2));
            float4 zv1 = *(const float4*)(z + (size_t)(row0 + 1) * D_ + (k << 8) + (lane << 2));
            #pragma unroll
            for (int c = 0; c < CD_; ++c) {
                float4 w4 = *(const float4*)(lds + c * D_ + (k << 8) + (lane << 2));
                ze[0][c] = fmaf(zv0.x, w4.x, ze[0][c]);
                ze[0][c] = fmaf(zv0.y, w4.y, ze[0][c]);
                ze[0][c] = fmaf(zv0.z, w4.z, ze[0][c]);
                ze[0][c] = fmaf(zv0.w, w4.w, ze[0][c]);
                ze[1][c] = fmaf(zv1.x, w4.x, ze[1][c]);
                ze[1][c] = fmaf(zv1.y, w4.y, ze[1][c]);
                ze[1][c] = fmaf(zv1.z, w4.z, ze[1][c]);
                ze[1][c] = fmaf(zv1.w, w4.w, ze[1][c]);
            }
        }

        // ---- wave-sum each partial (replicates z_e on all lanes) ----
        #pragma unroll
        for (int r = 0; r < 2; ++r) {
            #pragma unroll
            for (int c = 0; c < CD_; ++c) {
                float v = ze[r][c];
                v += __shfl_xor(v, 1, 64);
                v += __shfl_xor(v, 2, 64);
                v += __shfl_xor(v, 4, 64);
                v += __shfl_xor(v, 8, 64);
                v += __shfl_xor(v, 16, 64);
                v += __shfl_xor(v, 32, 64);
                ze[r][c] = v + bia[c];
            }
        }

        // ---- row norms; fold 2/||ze|| into the score ----
        float tw[2];
        #pragma unroll
        for (int r = 0; r < 2; ++r) {
            float s = 0.f;
            #pragma unroll
            for (int c = 0; c < CD_; ++c) s = fmaf(ze[r][c], ze[r][c], s);
            tw[r] = 2.f / fmaxf(EPSF, sqrtf(s));
        }

        // ---- scan 1024 codes: lane handles j = 4*lane + 256*m (+e) ----
        float bs[2] = {-1e38f, -1e38f};
        int   bj[2] = {0, 0};
        #pragma unroll
        for (int m = 0; m < 4; ++m) {
            float dt0[2], dt1[2], dt2[2], dt3[2];
            #pragma unroll
            for (int r = 0; r < 2; ++r) { dt0[r] = dt1[r] = dt2[r] = dt3[r] = 0.f; }
            #pragma unroll
            for (int c = 0; c < CD_; ++c) {
                float4 v4 = *(const float4*)(lds + CD_ * D_ + c * CS_ + (m << 8) + (lane << 2));
                #pragma unroll
                for (int r = 0; r < 2; ++r) {
                    dt0[r] = fmaf(v4.x, ze[r][c], dt0[r]);
                    dt1[r] = fmaf(v4.y, ze[r][c], dt1[r]);
                    dt2[r] = fmaf(v4.z, ze[r][c], dt2[r]);
                    dt3[r] = fmaf(v4.w, ze[r][c], dt3[r]);
                }
            }
            int j0 = (m << 8) + (lane << 2);
            #pragma unroll
            for (int r = 0; r < 2; ++r) {
                float s0 = fmaf(dt0[r], tw[r], -cn2[m].x);
                if (s0 > bs[r]) { bs[r] = s0; bj[r] = j0; }
                float s1 = fmaf(dt1[r], tw[r], -cn2[m].y);
                if (s1 > bs[r]) { bs[r] = s1; bj[r] = j0 + 1; }
                float s2 = fmaf(dt2[r], tw[r], -cn2[m].z);
                if (s2 > bs[r]) { bs[r] = s2; bj[r] = j0 + 2; }
                float s3 = fmaf(dt3[r], tw[r], -cn2[m].w);
                if (s3 > bs[r]) { bs[r] = s3; bj[r] = j0 + 3; }
            }
        }

        // ---- cross-lane argmax (tie -> smaller j, matches np.argmax first-max) ----
        #pragma unroll
        for (int r = 0; r < 2; ++r) {
            #pragma unroll
            for (int mlog = 0; mlog < 6; ++mlog) {
                int mk = 1 << mlog;
                float os = __shfl_xor(bs[r], mk, 64);
                int   oj = __shfl_xor(bj[r], mk, 64);
                bool take = (os > bs[r]) || (os == bs[r] && oj < bj[r]);
                bs[r] = take ? os : bs[r];
                bj[r] = take ? oj : bj[r];
            }
        }

        // ---- losses: sum (z_e - z_q)^2 over 2 rows x 8 dims ----
        float lsum = 0.f;
        #pragma unroll
        for (int r = 0; r < 2; ++r) {
            #pragma unroll
            for (int c = 0; c < CD_; ++c) {
                float q = cb[bj[r] * CD_ + c];   // raw codebook (broadcast load)
                float d = ze[r][c] - q;
                lsum = fmaf(d, d, lsum);
            }
        }
        if (lane == 0) {
            float v = lsum * (1.f / 32768.f);   // mean over T*CD per batch b
            int b = row0 >> 12;
            atomicAdd(dout + COMMIT_OFF + b, v);
            atomicAdd(dout + CBLOSS_OFF + b, v);
        }

        // ---- write z_e + indices (static register indices: one lane per row) ----
        if (lane == 0) {
            *(float4*)(dout + ZE_OFF + (size_t)row0 * CD_) =
                make_float4(ze[0][0], ze[0][1], ze[0][2], ze[0][3]);
            *(float4*)(dout + ZE_OFF + (size_t)row0 * CD_ + 4) =
                make_float4(ze[0][4], ze[0][5], ze[0][6], ze[0][7]);
            dout[IDX_OFF + row0] = (float)bj[0];
            idx_out[row0] = bj[0];
        }
        if (lane == 1) {
            *(float4*)(dout + ZE_OFF + (size_t)(row0 + 1) * CD_) =
                make_float4(ze[1][0], ze[1][1], ze[1][2], ze[1][3]);
            *(float4*)(dout + ZE_OFF + (size_t)(row0 + 1) * CD_ + 4) =
                make_float4(ze[1][4], ze[1][5], ze[1][6], ze[1][7]);
            dout[IDX_OFF + row0 + 1] = (float)bj[1];
            idx_out[row0 + 1] = bj[1];
        }
    }
}

// ---------------------------------------------------------------------------
// Out projection: out = codebook[idx] @ out_w + out_b   (write-bound)
// ---------------------------------------------------------------------------
__global__ __launch_bounds__(256)
void vq_out(const float* __restrict__ cb, const float* __restrict__ ws,
            const float* __restrict__ out_b, const int* __restrict__ idx,
            float* __restrict__ out) {
    int t = threadIdx.x;
    int lane = t & 63;
    int wv = (blockIdx.x << 2) + (t >> 6);  // 0..4095
    const float* ow = ws + WS_OUTW;

    float4 ob[4];
    #pragma unroll
    for (int k = 0; k < 4; ++k)
        ob[k] = *(const float4*)(out_b + (k << 8) + (lane << 2));

    for (int it = 0; it < 4; ++it) {
        int bi = wv + (it << 12);
        int row0 = bi << 2;

        float zq[4][CD_];
        #pragma unroll
        for (int r = 0; r < 4; ++r) {
            int j = idx[row0 + r];
            #pragma unroll
            for (int c = 0; c < CD_; ++c) zq[r][c] = cb[j * CD_ + c];
        }

        #pragma unroll
        for (int k = 0; k < 4; ++k) {
            float4 a0 = ob[k], a1 = ob[k], a2 = ob[k], a3 = ob[k];
            #pragma unroll
            for (int c = 0; c < CD_; ++c) {
                float4 w4 = *(const float4*)(ow + c * D_ + (k << 8) + (lane << 2));
                a0.x = fmaf(zq[0][c], w4.x, a0.x); a0.y = fmaf(zq[0][c], w4.y, a0.y);
                a0.z = fmaf(zq[0][c], w4.z, a0.z); a0.w = fmaf(zq[0][c], w4.w, a0.w);
                a1.x = fmaf(zq[1][c], w4.x, a1.x); a1.y = fmaf(zq[1][c], w4.y, a1.y);
                a1.z = fmaf(zq[1][c], w4.z, a1.z); a1.w = fmaf(zq[1][c], w4.w, a1.w);
                a2.x = fmaf(zq[2][c], w4.x, a2.x); a2.y = fmaf(zq[2][c], w4.y, a2.y);
                a2.z = fmaf(zq[2][c], w4.z, a2.z); a2.w = fmaf(zq[2][c], w4.w, a2.w);
                a3.x = fmaf(zq[3][c], w4.x, a3.x); a3.y = fmaf(zq[3][c], w4.y, a3.y);
                a3.z = fmaf(zq[3][c], w4.z, a3.z); a3.w = fmaf(zq[3][c], w4.w, a3.w);
            }
            size_t base = (size_t)row0 * D_ + (k << 8) + (lane << 2);
            *(float4*)(out + base)            = a0;
            *(float4*)(out + base + D_)       = a1;
            *(float4*)(out + base + 2 * D_)   = a2;
            *(float4*)(out + base + 3 * D_)   = a3;
        }
    }
}

extern "C" void kernel_launch(void* const* d_in, const int* in_sizes, int n_in,
                              void* d_out, int out_size, void* d_ws, size_t ws_size,
                              hipStream_t stream) {
    const float* z     = (const float*)d_in[0];
    const float* in_v  = (const float*)d_in[1];
    const float* in_g  = (const float*)d_in[2];
    const float* in_b  = (const float*)d_in[3];
    const float* out_v = (const float*)d_in[4];
    const float* out_g = (const float*)d_in[5];
    const float* out_b = (const float*)d_in[6];
    const float* cb    = (const float*)d_in[7];
    float* dout = (float*)d_out;
    float* ws   = (float*)d_ws;
    int* idxp   = (int*)(ws + WS_IDX);

    vq_prep<<<1, 1024, 0, stream>>>(in_v, in_g, out_v, out_g, cb, ws, dout);
    vq_main<<<1024, 512, 0, stream>>>(z, in_b, cb, ws, dout, idxp);
    vq_out<<<1024, 256, 0, stream>>>(cb, ws, out_b, idxp, dout + OUT_OFF);
}

// Round 3
// 193.130 us; speedup vs baseline: 3.7617x; 3.4779x over previous
//
#include <hip/hip_runtime.h>

#define B_    16
#define T_    4096
#define D_    1024
#define CD_   8
#define CS_   1024
#define NROWS 65536
#define EPSF  1e-12f

// ---- d_out float offsets (outputs concatenated flat in return order) ----
#define OUT_OFF    0           // [16,4096,1024] = 67108864
#define COMMIT_OFF 67108864    // [16]
#define CBLOSS_OFF 67108880    // [16]
#define IDX_OFF    67108896    // [16,4096] as float
#define ZE_OFF     67174432    // [16,4096,8]

// ---- ws float offsets ----
#define WS_INWT 0        // in_wT   [8][1024]  (c-major)
#define WS_CBR  8192     // cbn_row [1024][8]  (row-major normalized codebook)
#define WS_OUTW 16384    // out_w   [8][1024]  (c-major)
#define WS_CN2  24576    // ||cbn_j||^2 [1024]
#define WS_IDX  25600    // indices as int [65536]

// ---------------------------------------------------------------------------
// Prep: weight-norm both matrices, normalize codebook, zero losses
// ---------------------------------------------------------------------------
__global__ __launch_bounds__(1024)
void vq_prep(const float* __restrict__ in_v, const float* __restrict__ in_g,
             const float* __restrict__ out_v, const float* __restrict__ out_g,
             const float* __restrict__ cb, float* __restrict__ ws,
             float* __restrict__ dout) {
    int t = threadIdx.x;
    int lane = t & 63;
    int wid = t >> 6;
    __shared__ float normIn[CD_];

    // column norms of in_v (sum over d per c): wave w handles column w
    if (wid < CD_) {
        float s = 0.f;
        #pragma unroll
        for (int i = 0; i < D_ / 64; ++i) {
            float v = in_v[(size_t)(lane + 64 * i) * CD_ + wid];
            s = fmaf(v, v, s);
        }
        #pragma unroll
        for (int m = 1; m <= 32; m <<= 1) s += __shfl_xor(s, m, 64);
        if (lane == 0) normIn[wid] = sqrtf(s);
    }
    __syncthreads();

    // in_wT[c][d] = in_g[c] * in_v[d][c] / max(eps, norm_c)
    #pragma unroll
    for (int rep = 0; rep < (CD_ * D_) / 1024; ++rep) {
        int idx = rep * 1024 + t;
        int c = idx >> 10, d = idx & (D_ - 1);
        ws[WS_INWT + idx] = in_g[c] * in_v[(size_t)d * CD_ + c] / fmaxf(EPSF, normIn[c]);
    }

    // out_w[c][d] = out_g[d] * out_v[c][d] / max(eps, norm_d)   (norm over c)
    {
        int d = t;  // blockDim == 1024 == D_
        float v[CD_]; float s = 0.f;
        #pragma unroll
        for (int c = 0; c < CD_; ++c) { v[c] = out_v[c * D_ + d]; s = fmaf(v[c], v[c], s); }
        float n = fmaxf(EPSF, sqrtf(s));
        float g = out_g[d];
        #pragma unroll
        for (int c = 0; c < CD_; ++c) ws[WS_OUTW + c * D_ + d] = g * v[c] / n;
    }

    // cbn_row[j][c] = cb[j][c] / max(eps, ||cb_j||);  cn2[j] = sum_c cbn^2
    {
        int j = t;  // blockDim == 1024 == CS_
        float v[CD_]; float s = 0.f;
        #pragma unroll
        for (int c = 0; c < CD_; ++c) { v[c] = cb[j * CD_ + c]; s = fmaf(v[c], v[c], s); }
        float n = fmaxf(EPSF, sqrtf(s));
        float n2 = 0.f;
        #pragma unroll
        for (int c = 0; c < CD_; ++c) {
            float q = v[c] / n;
            ws[WS_CBR + j * CD_ + c] = q;
            n2 = fmaf(q, q, n2);
        }
        ws[WS_CN2 + j] = n2;
    }

    // zero the 32 loss accumulators
    if (t < 32) dout[COMMIT_OFF + t] = 0.f;
}

// ---------------------------------------------------------------------------
// Stage 1: z_e = z @ in_wT + in_b. Pure streaming GEMV, tiny live set.
// Math sequence bit-identical to the passing round-2 kernel.
// ---------------------------------------------------------------------------
__global__ __launch_bounds__(256)
void vq_ze(const float* __restrict__ z, const float* __restrict__ in_b,
           const float* __restrict__ ws, float* __restrict__ dout) {
    __shared__ float lds[CD_ * D_];  // in_wT, 32 KB
    int t = threadIdx.x;
    #pragma unroll
    for (int i = 0; i < 8; ++i)
        ((float4*)lds)[i * 256 + t] = ((const float4*)ws)[i * 256 + t];
    __syncthreads();

    int lane = t & 63;
    int wv = (blockIdx.x << 2) + (t >> 6);  // 0..8191

    float bia[CD_];
    #pragma unroll
    for (int c = 0; c < CD_; ++c) bia[c] = in_b[c];

    for (int it = 0; it < 4; ++it) {
        int bi = wv + (it << 13);   // 0..32767
        int row0 = bi << 1;         // 2 consecutive rows

        float ze[2][CD_];
        #pragma unroll
        for (int r = 0; r < 2; ++r)
            #pragma unroll
            for (int c = 0; c < CD_; ++c) ze[r][c] = 0.f;

        #pragma unroll
        for (int k = 0; k < 4; ++k) {
            float4 zv0 = *(const float4*)(z + (size_t)(row0)     * D_ + (k << 8) + (lane << 2));
            float4 zv1 = *(const float4*)(z + (size_t)(row0 + 1) * D_ + (k << 8) + (lane << 2));
            #pragma unroll
            for (int c = 0; c < CD_; ++c) {
                float4 w4 = *(const float4*)(lds + c * D_ + (k << 8) + (lane << 2));
                ze[0][c] = fmaf(zv0.x, w4.x, ze[0][c]);
                ze[0][c] = fmaf(zv0.y, w4.y, ze[0][c]);
                ze[0][c] = fmaf(zv0.z, w4.z, ze[0][c]);
                ze[0][c] = fmaf(zv0.w, w4.w, ze[0][c]);
                ze[1][c] = fmaf(zv1.x, w4.x, ze[1][c]);
                ze[1][c] = fmaf(zv1.y, w4.y, ze[1][c]);
                ze[1][c] = fmaf(zv1.z, w4.z, ze[1][c]);
                ze[1][c] = fmaf(zv1.w, w4.w, ze[1][c]);
            }
        }

        #pragma unroll
        for (int r = 0; r < 2; ++r) {
            #pragma unroll
            for (int c = 0; c < CD_; ++c) {
                float v = ze[r][c];
                v += __shfl_xor(v, 1, 64);
                v += __shfl_xor(v, 2, 64);
                v += __shfl_xor(v, 4, 64);
                v += __shfl_xor(v, 8, 64);
                v += __shfl_xor(v, 16, 64);
                v += __shfl_xor(v, 32, 64);
                ze[r][c] = v + bia[c];
            }
        }

        if (lane == 0) {
            *(float4*)(dout + ZE_OFF + (size_t)row0 * CD_) =
                make_float4(ze[0][0], ze[0][1], ze[0][2], ze[0][3]);
            *(float4*)(dout + ZE_OFF + (size_t)row0 * CD_ + 4) =
                make_float4(ze[0][4], ze[0][5], ze[0][6], ze[0][7]);
        }
        if (lane == 1) {
            *(float4*)(dout + ZE_OFF + (size_t)(row0 + 1) * CD_) =
                make_float4(ze[1][0], ze[1][1], ze[1][2], ze[1][3]);
            *(float4*)(dout + ZE_OFF + (size_t)(row0 + 1) * CD_ + 4) =
                make_float4(ze[1][4], ze[1][5], ze[1][6], ze[1][7]);
        }
    }
}

// ---------------------------------------------------------------------------
// Stage 2: one row per LANE. Codebook scan via wave-uniform LDS broadcasts,
// zero shuffles in the hot loop. Same score fma ordering / values as before
// -> bit-identical argmax (strict >, ascending j = first-max tie policy).
// ---------------------------------------------------------------------------
__global__ __launch_bounds__(256)
void vq_scan(const float* __restrict__ ze_in, const float* __restrict__ cb,
             const float* __restrict__ ws, float* __restrict__ dout,
             int* __restrict__ idx_out) {
    __shared__ float s_cb[CS_ * CD_];  // 32 KB, row-major normalized codebook
    __shared__ float s_c2[CS_];        // 4 KB
    int t = threadIdx.x;
    #pragma unroll
    for (int i = 0; i < 8; ++i)
        ((float4*)s_cb)[i * 256 + t] = ((const float4*)(ws + WS_CBR))[i * 256 + t];
    ((float4*)s_c2)[t] = ((const float4*)(ws + WS_CN2))[t];
    __syncthreads();

    int row = blockIdx.x * 256 + t;

    float4 a = *(const float4*)(ze_in + (size_t)row * CD_);
    float4 b = *(const float4*)(ze_in + (size_t)row * CD_ + 4);

    float s = 0.f;
    s = fmaf(a.x, a.x, s); s = fmaf(a.y, a.y, s);
    s = fmaf(a.z, a.z, s); s = fmaf(a.w, a.w, s);
    s = fmaf(b.x, b.x, s); s = fmaf(b.y, b.y, s);
    s = fmaf(b.z, b.z, s); s = fmaf(b.w, b.w, s);
    float tw = 2.f / fmaxf(EPSF, sqrtf(s));

    float bs = -1e38f;
    int bj = 0;
    #pragma unroll 4
    for (int j = 0; j < CS_; ++j) {
        float4 ca = ((const float4*)s_cb)[j * 2];
        float4 cbv = ((const float4*)s_cb)[j * 2 + 1];
        float dot = 0.f;
        dot = fmaf(ca.x,  a.x, dot);
        dot = fmaf(ca.y,  a.y, dot);
        dot = fmaf(ca.z,  a.z, dot);
        dot = fmaf(ca.w,  a.w, dot);
        dot = fmaf(cbv.x, b.x, dot);
        dot = fmaf(cbv.y, b.y, dot);
        dot = fmaf(cbv.z, b.z, dot);
        dot = fmaf(cbv.w, b.w, dot);
        float sc = fmaf(dot, tw, -s_c2[j]);
        if (sc > bs) { bs = sc; bj = j; }
    }

    // losses: (z_e - codebook[bj])^2 summed over c, reduced per wave
    const float* q = cb + (size_t)bj * CD_;
    float lsum = 0.f;
    {
        float d0 = a.x - q[0]; lsum = fmaf(d0, d0, lsum);
        float d1 = a.y - q[1]; lsum = fmaf(d1, d1, lsum);
        float d2 = a.z - q[2]; lsum = fmaf(d2, d2, lsum);
        float d3 = a.w - q[3]; lsum = fmaf(d3, d3, lsum);
        float d4 = b.x - q[4]; lsum = fmaf(d4, d4, lsum);
        float d5 = b.y - q[5]; lsum = fmaf(d5, d5, lsum);
        float d6 = b.z - q[6]; lsum = fmaf(d6, d6, lsum);
        float d7 = b.w - q[7]; lsum = fmaf(d7, d7, lsum);
    }
    lsum += __shfl_xor(lsum, 1, 64);
    lsum += __shfl_xor(lsum, 2, 64);
    lsum += __shfl_xor(lsum, 4, 64);
    lsum += __shfl_xor(lsum, 8, 64);
    lsum += __shfl_xor(lsum, 16, 64);
    lsum += __shfl_xor(lsum, 32, 64);
    if ((t & 63) == 0) {
        float v = lsum * (1.f / 32768.f);
        int bt = row >> 12;
        atomicAdd(dout + COMMIT_OFF + bt, v);
        atomicAdd(dout + CBLOSS_OFF + bt, v);
    }

    dout[IDX_OFF + row] = (float)bj;
    idx_out[row] = bj;
}

// ---------------------------------------------------------------------------
// Out projection: out = codebook[idx] @ out_w + out_b   (write-bound)
// ---------------------------------------------------------------------------
__global__ __launch_bounds__(256)
void vq_out(const float* __restrict__ cb, const float* __restrict__ ws,
            const float* __restrict__ out_b, const int* __restrict__ idx,
            float* __restrict__ out) {
    int t = threadIdx.x;
    int lane = t & 63;
    int wv = (blockIdx.x << 2) + (t >> 6);  // 0..4095
    const float* ow = ws + WS_OUTW;

    float4 ob[4];
    #pragma unroll
    for (int k = 0; k < 4; ++k)
        ob[k] = *(const float4*)(out_b + (k << 8) + (lane << 2));

    for (int it = 0; it < 4; ++it) {
        int bi = wv + (it << 12);
        int row0 = bi << 2;

        float zq[4][CD_];
        #pragma unroll
        for (int r = 0; r < 4; ++r) {
            int j = idx[row0 + r];
            #pragma unroll
            for (int c = 0; c < CD_; ++c) zq[r][c] = cb[j * CD_ + c];
        }

        #pragma unroll
        for (int k = 0; k < 4; ++k) {
            float4 a0 = ob[k], a1 = ob[k], a2 = ob[k], a3 = ob[k];
            #pragma unroll
            for (int c = 0; c < CD_; ++c) {
                float4 w4 = *(const float4*)(ow + c * D_ + (k << 8) + (lane << 2));
                a0.x = fmaf(zq[0][c], w4.x, a0.x); a0.y = fmaf(zq[0][c], w4.y, a0.y);
                a0.z = fmaf(zq[0][c], w4.z, a0.z); a0.w = fmaf(zq[0][c], w4.w, a0.w);
                a1.x = fmaf(zq[1][c], w4.x, a1.x); a1.y = fmaf(zq[1][c], w4.y, a1.y);
                a1.z = fmaf(zq[1][c], w4.z, a1.z); a1.w = fmaf(zq[1][c], w4.w, a1.w);
                a2.x = fmaf(zq[2][c], w4.x, a2.x); a2.y = fmaf(zq[2][c], w4.y, a2.y);
                a2.z = fmaf(zq[2][c], w4.z, a2.z); a2.w = fmaf(zq[2][c], w4.w, a2.w);
                a3.x = fmaf(zq[3][c], w4.x, a3.x); a3.y = fmaf(zq[3][c], w4.y, a3.y);
                a3.z = fmaf(zq[3][c], w4.z, a3.z); a3.w = fmaf(zq[3][c], w4.w, a3.w);
            }
            size_t base = (size_t)row0 * D_ + (k << 8) + (lane << 2);
            *(float4*)(out + base)            = a0;
            *(float4*)(out + base + D_)       = a1;
            *(float4*)(out + base + 2 * D_)   = a2;
            *(float4*)(out + base + 3 * D_)   = a3;
        }
    }
}

extern "C" void kernel_launch(void* const* d_in, const int* in_sizes, int n_in,
                              void* d_out, int out_size, void* d_ws, size_t ws_size,
                              hipStream_t stream) {
    const float* z     = (const float*)d_in[0];
    const float* in_v  = (const float*)d_in[1];
    const float* in_g  = (const float*)d_in[2];
    const float* in_b  = (const float*)d_in[3];
    const float* out_v = (const float*)d_in[4];
    const float* out_g = (const float*)d_in[5];
    const float* out_b = (const float*)d_in[6];
    const float* cb    = (const float*)d_in[7];
    float* dout = (float*)d_out;
    float* ws   = (float*)d_ws;
    int* idxp   = (int*)(ws + WS_IDX);

    vq_prep<<<1, 1024, 0, stream>>>(in_v, in_g, out_v, out_g, cb, ws, dout);
    vq_ze<<<2048, 256, 0, stream>>>(z, in_b, ws, dout);
    vq_scan<<<256, 256, 0, stream>>>(dout + ZE_OFF, cb, ws, dout, idxp);
    vq_out<<<1024, 256, 0, stream>>>(cb, ws, out_b, idxp, dout + OUT_OFF);
}